// Round 17
// baseline (301.861 us; speedup 1.0000x reference)
//
#include <hip/hip_runtime.h>

#define NN 50000
#define EE 500000
#define CAP 64  // per-dst slot capacity; deg ~ Poisson(10), P(deg>=64) ~ e^-65

typedef unsigned int u32;
typedef unsigned short ushort;
typedef __attribute__((ext_vector_type(8))) short short8v;
typedef __attribute__((ext_vector_type(4))) float float4v;

__device__ __forceinline__ ushort f2b(float f) {  // f32 -> bf16 RNE
  u32 u = __float_as_uint(f);
  u32 r = (u + 0x7fffu + ((u >> 16) & 1u)) >> 16;
  return (ushort)r;
}
__device__ __forceinline__ u32 pk2(float a, float b) {
  return (u32)f2b(a) | ((u32)f2b(b) << 16);
}
__device__ __forceinline__ float bl(u32 q) { return __uint_as_float(q << 16); }
__device__ __forceinline__ float bh(u32 q) { return __uint_as_float(q & 0xffff0000u); }
__device__ __forceinline__ void gload16(const void* g, void* l) {
  __builtin_amdgcn_global_load_lds((const __attribute__((address_space(1))) void*)g,
                                   (__attribute__((address_space(3))) void*)l, 16, 0, 0);
}

// -------- prep: WT transpose | V6T fold | pad | xb convert + cnt3 zero --------
__global__ void prep_kernel(const float* __restrict__ W_gp, const float* __restrict__ W_pg,
                            const float* __restrict__ W_gg,
                            const float* __restrict__ as_gp, const float* __restrict__ as_pg,
                            const float* __restrict__ as_gg,
                            const float* __restrict__ ad_gp, const float* __restrict__ ad_pg,
                            const float* __restrict__ ad_gg,
                            const float* __restrict__ xg, const float* __restrict__ xp,
                            ushort* __restrict__ WT, ushort* __restrict__ V6T,
                            ushort* __restrict__ xb, int* __restrict__ cnt3) {
  int b = blockIdx.x;
  int k = threadIdx.x;
  if (b < 256) {  // weight transposes: WT[p][n][k] = W_p[k][n]
    int n = b;
    WT[(size_t)0 * 65536 + n * 256 + k] = f2b(W_gp[k * 256 + n]);
    WT[(size_t)1 * 65536 + n * 256 + k] = f2b(W_pg[k * 256 + n]);
    WT[(size_t)2 * 65536 + n * 256 + k] = f2b(W_gg[k * 256 + n]);
    return;
  }
  if (b < 304) {  // V6T fold: one block per (g,h); v[k] = sum_c W[k][32h+c]*a[h][c]
    int idx = b - 256;
    int g = idx >> 3, h = idx & 7;
    const float* W;
    const float* a;
    switch (g) {
      case 0: W = W_gp; a = as_gp; break;  // als gp (gene rows)
      case 1: W = W_gg; a = as_gg; break;  // als gg (gene rows)
      case 2: W = W_pg; a = ad_pg; break;  // ald pg (gene rows, dst)
      case 3: W = W_gg; a = ad_gg; break;  // ald gg (gene rows, dst)
      case 4: W = W_pg; a = as_pg; break;  // als pg (pheno rows)
      default: W = W_gp; a = ad_gp; break; // ald gp (pheno rows, dst)
    }
    const float4* wrow = (const float4*)&W[(size_t)k * 256 + h * 32];
    const float4* arow = (const float4*)&a[h * 32];
    float s = 0.f;
#pragma unroll
    for (int q = 0; q < 8; ++q) {
      float4 wv = wrow[q];
      float4 av = arow[q];
      s += wv.x * av.x + wv.y * av.y + wv.z * av.z + wv.w * av.w;
    }
    V6T[(size_t)(g * 8 + h) * 256 + k] = f2b(s);
    return;
  }
  if (b == 304) {  // pad cols 48..63
#pragma unroll
    for (int col = 48; col < 64; ++col) V6T[(size_t)col * 256 + k] = 0;
    return;
  }
  // xb convert + cnt3 zero (prep precedes fused_compute, so ordering holds)
  int gid = (b - 305) * 256 + k;
  const int gstride = 2048 * 256;
  for (int j = gid; j < 3 * NN; j += gstride) cnt3[j] = 0;
  const int tot = 2 * NN * 64;
  for (int i = gid; i < tot; i += gstride) {
    const float* src = (i < NN * 64) ? xg + (size_t)i * 4 : xp + ((size_t)i - (size_t)NN * 64) * 4;
    float4 v = *(const float4*)src;
    ushort4 o;
    o.x = f2b(v.x); o.y = f2b(v.y); o.z = f2b(v.z); o.w = f2b(v.w);
    *(ushort4*)&xb[(size_t)i * 4] = o;
  }
}

// ---------------- fused compute: y==0 bucket-permute | y in [1,6] h-GEMM (128x128) | y==7 al ----------------
__global__ __launch_bounds__(256) void fused_compute(
    const ushort* __restrict__ xb, const ushort* __restrict__ WT,
    const ushort* __restrict__ V6T, ushort* __restrict__ hb3,
    ushort* __restrict__ alsb, float* __restrict__ ald3,
    const int* __restrict__ e0, const int* __restrict__ e1, const int* __restrict__ e2,
    int* __restrict__ cnt3, int* __restrict__ srcs3) {
  __shared__ ushort smem[16384];  // 32 KB: GEMM As 2x4096 | Bs 2x4096 ; al uses first 2x2048
  const int tid = threadIdx.x;
  const int l = tid & 63, w = tid >> 6;
  const int rr = l & 15, kb = l >> 4;
  if (blockIdx.y == 0) {
    // bucket permute: srcs3[slot*CAP + cnt3[slot]++] = src  (cnt3 zeroed by prep)
    const int stride = 391 * 256;
    for (int i = blockIdx.x * 256 + tid; i < 3 * EE; i += stride) {
      int which = i >= 2 * EE ? 2 : (i >= EE ? 1 : 0);
      const int* ei = which == 0 ? e0 : (which == 1 ? e1 : e2);
      int e = i - which * EE;
      int d = ei[EE + e];
      int gslot = which * NN + d;
      int pos = atomicAdd(&cnt3[gslot], 1);
      if (pos < CAP) srcs3[(size_t)gslot * CAP + pos] = ei[e];
    }
    return;
  }
  if (blockIdx.y < 7) {
    ushort* As = smem;          // [2][4096]
    ushort* Bs = smem + 8192;   // [2][4096]
    const int yy = blockIdx.y - 1;
    const int p = yy >> 1;
    const int c0 = (yy & 1) * 128;
    const ushort* x = xb + (p == 1 ? (size_t)NN * 256 : 0);
    const ushort* Wp = WT + (size_t)p * 65536 + (size_t)c0 * 256;
    ushort* hb = hb3 + (size_t)p * 12800000;
    const int r0 = blockIdx.x * 128;
    const int wm = w >> 1, wn = w & 1;
    float4v acc[4][4];
#pragma unroll
    for (int mi = 0; mi < 4; ++mi)
#pragma unroll
      for (int ni = 0; ni < 4; ++ni) acc[mi][ni] = (float4v){0.f, 0.f, 0.f, 0.f};
    const int r1 = tid >> 2, g1 = tid & 3;
    const int r2 = 64 + (tid >> 2), g2 = tid & 3;

#define STAGE(buf, k0)                                                               \
  {                                                                                  \
    gload16(&x[(size_t)(r0 + r1) * 256 + (k0) + g1 * 8], &As[(buf) * 4096 + tid * 8]); \
    gload16(&x[(size_t)(r0 + r2) * 256 + (k0) + g2 * 8], &As[(buf) * 4096 + (tid + 256) * 8]); \
    gload16(&Wp[(size_t)r1 * 256 + (k0) + g1 * 8], &Bs[(buf) * 4096 + tid * 8]);     \
    gload16(&Wp[(size_t)r2 * 256 + (k0) + g2 * 8], &Bs[(buf) * 4096 + (tid + 256) * 8]); \
  }

    STAGE(0, 0);
    __syncthreads();
#pragma unroll
    for (int k = 0; k < 8; ++k) {
      const int buf = k & 1;
      if (k < 7) STAGE(buf ^ 1, (k + 1) * 32);
      short8v af[4], bf[4];
#pragma unroll
      for (int t = 0; t < 4; ++t) {
        af[t] = *(const short8v*)&As[buf * 4096 + (wm * 64 + t * 16 + rr) * 32 + kb * 8];
        bf[t] = *(const short8v*)&Bs[buf * 4096 + (wn * 64 + t * 16 + rr) * 32 + kb * 8];
      }
#pragma unroll
      for (int mi = 0; mi < 4; ++mi)
#pragma unroll
        for (int ni = 0; ni < 4; ++ni)
          acc[mi][ni] = __builtin_amdgcn_mfma_f32_16x16x32_bf16(bf[ni], af[mi], acc[mi][ni], 0, 0, 0);
      __syncthreads();
    }
#undef STAGE
#pragma unroll
    for (int mi = 0; mi < 4; ++mi) {
      const int row = r0 + wm * 64 + mi * 16 + rr;
      if (row < NN) {
        ushort* hp = &hb[(size_t)row * 256 + c0 + wn * 64 + kb * 4];
#pragma unroll
        for (int ni = 0; ni < 4; ++ni) {
          uint2 o;
          o.x = pk2(acc[mi][ni][0], acc[mi][ni][1]);
          o.y = pk2(acc[mi][ni][2], acc[mi][ni][3]);
          *(uint2*)&hp[ni * 16] = o;
        }
      }
    }
    return;
  }
  // ---- al slice: 256 rows per block; V6T fragments preloaded to registers (L2-hot,
  //      no LDS staging -> no 16-way bank conflicts on the 512B-stride reads) ----
  ushort* As2 = smem;  // [2][2048]
  short8v bfv[8];
#pragma unroll
  for (int k = 0; k < 8; ++k) {
    uint4 q = *(const uint4*)&V6T[(size_t)(w * 16 + rr) * 256 + k * 32 + kb * 8];
    bfv[k] = *(short8v*)&q;
  }
  for (int t = 0; t < 4; ++t) {
    const int r0 = blockIdx.x * 256 + t * 64;
    gload16(&xb[(size_t)(r0 + (tid >> 2)) * 256 + (tid & 3) * 8], &As2[tid * 8]);
    __syncthreads();
    float4v acc[4];
#pragma unroll
    for (int mi = 0; mi < 4; ++mi) acc[mi] = (float4v){0.f, 0.f, 0.f, 0.f};
#pragma unroll
    for (int k = 0; k < 8; ++k) {
      const int buf = k & 1;
      if (k < 7)
        gload16(&xb[(size_t)(r0 + (tid >> 2)) * 256 + (k + 1) * 32 + (tid & 3) * 8],
                &As2[(buf ^ 1) * 2048 + tid * 8]);
#pragma unroll
      for (int mi = 0; mi < 4; ++mi) {
        short8v afv = *(const short8v*)&As2[buf * 2048 + (mi * 16 + rr) * 32 + kb * 8];
        acc[mi] = __builtin_amdgcn_mfma_f32_16x16x32_bf16(bfv[k], afv, acc[mi], 0, 0, 0);
      }
      __syncthreads();
    }
    // lane holds D[row=r0+mi*16+rr][col=w*16+kb*4+i]; g=w*2+(kb>>1); idx=(kb&1)*4
    const int g = w * 2 + (kb >> 1);
    const int idx = (kb & 1) * 4;
#pragma unroll
    for (int mi = 0; mi < 4; ++mi) {
      int grow = r0 + mi * 16 + rr;
      float4 val = make_float4(acc[mi][0], acc[mi][1], acc[mi][2], acc[mi][3]);
      if (grow < NN) {
        if (g == 0 || g == 1) {
          ushort* arr = alsb + (g == 0 ? 0 : 800000);
          uint2 o;
          o.x = pk2(val.x, val.y);
          o.y = pk2(val.z, val.w);
          *(uint2*)&arr[(size_t)grow * 8 + idx] = o;
        } else if (g == 2 || g == 3) {
          float* arr = ald3 + (g == 2 ? 400000 : 800000);
          *(float4*)&arr[(size_t)grow * 8 + idx] = val;
        }
      } else if (grow < 2 * NN) {
        int r = grow - NN;
        if (g == 4) {
          uint2 o;
          o.x = pk2(val.x, val.y);
          o.y = pk2(val.z, val.w);
          *(uint2*)&alsb[400000 + (size_t)r * 8 + idx] = o;
        } else if (g == 5) {
          *(float4*)&ald3[(size_t)r * 8 + idx] = val;
        }
      }
    }
  }
}

// -------- gather+LN: one wave per output row; gene waves do pg+gg; fused LN --------
__global__ __launch_bounds__(256) void gat_gather_ln(
    const int* __restrict__ cnt3, const int* __restrict__ srcs3,
    const ushort* __restrict__ hb3, const ushort* __restrict__ alsb,
    const float* __restrict__ ald3, const ushort* __restrict__ xb,
    const float* __restrict__ b_gp, const float* __restrict__ b_pg,
    const float* __restrict__ b_gg,
    const float* __restrict__ lng_g, const float* __restrict__ lnb_g,
    const float* __restrict__ lng_p, const float* __restrict__ lnb_p,
    float* __restrict__ out) {
  __shared__ float exs[4][8][68];
  __shared__ int ssrc[4][64];
  const int l = threadIdx.x & 63;
  const int wv = threadIdx.x >> 6;
  const int slot = blockIdx.x * 4 + wv;
  if (slot >= 2 * NN) return;
  const bool gene = (slot < NN);
  const int d = gene ? slot : slot - NN;
  const int sl = l & 31;
  const int half = l >> 5;
  const int hh = sl >> 2;
  float vout[8] = {0.f, 0.f, 0.f, 0.f, 0.f, 0.f, 0.f, 0.f};
  const int nph = gene ? 2 : 1;
  for (int q = 0; q < nph; ++q) {
    const int phase = gene ? (1 + q) : 0;
    const int cslot = phase * NN + d;
    const ushort* hmat = hb3 + (size_t)phase * 12800000;
    const ushort* al_s = alsb + (size_t)phase * 400000;
    const float* al_d = ald3 + (size_t)phase * 400000;
    const int cnt = cnt3[cslot];
    if (cnt == 0) continue;
    const int* srow = srcs3 + (size_t)cslot * CAP;
    float4 ad0 = *(const float4*)&al_d[(size_t)d * 8];
    float4 ad1 = *(const float4*)&al_d[(size_t)d * 8 + 4];
    const float ald[8] = {ad0.x, ad0.y, ad0.z, ad0.w, ad1.x, ad1.y, ad1.z, ad1.w};
    float den = 0.f;
    float acc8[8] = {0.f, 0.f, 0.f, 0.f, 0.f, 0.f, 0.f, 0.f};
    const ushort* hrow = hmat + sl * 8;
    // cnt <= CAP = 64: single chunk
    {
      float ex[8] = {0.f, 0.f, 0.f, 0.f, 0.f, 0.f, 0.f, 0.f};
      int s = 0;
      if (l < cnt) {
        s = srow[l];
        uint4 sq = *(const uint4*)&al_s[(size_t)s * 8];
        float a[8] = {bl(sq.x) + ald[0], bh(sq.x) + ald[1], bl(sq.y) + ald[2], bh(sq.y) + ald[3],
                      bl(sq.z) + ald[4], bh(sq.z) + ald[5], bl(sq.w) + ald[6], bh(sq.w) + ald[7]};
#pragma unroll
        for (int h = 0; h < 8; ++h) ex[h] = __expf(fmaxf(a[h], 0.2f * a[h]));
      }
      ssrc[wv][l] = s;
#pragma unroll
      for (int h = 0; h < 8; ++h) exs[wv][h][l] = ex[h];
      // 2 edges per half in flight
      int chunkr = (cnt + 3) & ~3;
      for (int j = 0; j < chunkr; j += 4) {
        int ja = j + half, jb = j + 2 + half;
        int sa = ssrc[wv][ja], sb = ssrc[wv][jb];
        float wa = exs[wv][hh][ja], wb = exs[wv][hh][jb];
        uint4 pa = *(const uint4*)&hrow[(size_t)sa * 256];
        uint4 pb = *(const uint4*)&hrow[(size_t)sb * 256];
        den += wa + wb;
        acc8[0] += bl(pa.x) * wa + bl(pb.x) * wb;
        acc8[1] += bh(pa.x) * wa + bh(pb.x) * wb;
        acc8[2] += bl(pa.y) * wa + bl(pb.y) * wb;
        acc8[3] += bh(pa.y) * wa + bh(pb.y) * wb;
        acc8[4] += bl(pa.z) * wa + bl(pb.z) * wb;
        acc8[5] += bh(pa.z) * wa + bh(pb.z) * wb;
        acc8[6] += bl(pa.w) * wa + bl(pb.w) * wb;
        acc8[7] += bh(pa.w) * wa + bh(pb.w) * wb;
      }
    }
#pragma unroll
    for (int i = 0; i < 8; ++i) acc8[i] += __shfl_xor(acc8[i], 32);
    den += __shfl_xor(den, 32);
    float wd = 1.f / (den + 1e-16f);
#pragma unroll
    for (int i = 0; i < 8; ++i) vout[i] += acc8[i] * wd;
  }
  // residual (bf16 xb) + biases
  const ushort* xrow = xb + (gene ? 0 : (size_t)NN * 256) + (size_t)d * 256;
  uint4 xq = *(const uint4*)&xrow[sl * 8];
  float4 ba, bb;
  if (gene) {
    float4 p1 = *(const float4*)&b_pg[sl * 8];
    float4 p2 = *(const float4*)&b_pg[sl * 8 + 4];
    float4 q1 = *(const float4*)&b_gg[sl * 8];
    float4 q2 = *(const float4*)&b_gg[sl * 8 + 4];
    ba = make_float4(p1.x + q1.x, p1.y + q1.y, p1.z + q1.z, p1.w + q1.w);
    bb = make_float4(p2.x + q2.x, p2.y + q2.y, p2.z + q2.z, p2.w + q2.w);
  } else {
    ba = *(const float4*)&b_gp[sl * 8];
    bb = *(const float4*)&b_gp[sl * 8 + 4];
  }
  vout[0] += bl(xq.x) + ba.x; vout[1] += bh(xq.x) + ba.y;
  vout[2] += bl(xq.y) + ba.z; vout[3] += bh(xq.y) + ba.w;
  vout[4] += bl(xq.z) + bb.x; vout[5] += bh(xq.z) + bb.y;
  vout[6] += bl(xq.w) + bb.z; vout[7] += bh(xq.w) + bb.w;
  // LayerNorm over 256 ch (32 lanes x 8; halves duplicate)
  float s = 0.f, ss = 0.f;
#pragma unroll
  for (int i = 0; i < 8; ++i) { s += vout[i]; ss += vout[i] * vout[i]; }
#pragma unroll
  for (int off = 1; off < 32; off <<= 1) {
    s += __shfl_xor(s, off);
    ss += __shfl_xor(ss, off);
  }
  float mu = s * (1.f / 256.f);
  float var = ss * (1.f / 256.f) - mu * mu;
  float rstd = rsqrtf(var + 1e-5f);
  const float* lg = gene ? lng_g : lng_p;
  const float* lb = gene ? lnb_g : lnb_p;
  float4 g1 = *(const float4*)&lg[sl * 8];
  float4 g2 = *(const float4*)&lg[sl * 8 + 4];
  float4 c1 = *(const float4*)&lb[sl * 8];
  float4 c2 = *(const float4*)&lb[sl * 8 + 4];
  if (half == 0) {
    float* op = &out[(size_t)slot * 256 + sl * 8];
    float4 o1 = make_float4((vout[0] - mu) * rstd * g1.x + c1.x,
                            (vout[1] - mu) * rstd * g1.y + c1.y,
                            (vout[2] - mu) * rstd * g1.z + c1.z,
                            (vout[3] - mu) * rstd * g1.w + c1.w);
    float4 o2 = make_float4((vout[4] - mu) * rstd * g2.x + c2.x,
                            (vout[5] - mu) * rstd * g2.y + c2.y,
                            (vout[6] - mu) * rstd * g2.z + c2.z,
                            (vout[7] - mu) * rstd * g2.w + c2.w);
    *(float4*)op = o1;
    *(float4*)(op + 4) = o2;
  }
}

extern "C" void kernel_launch(void* const* d_in, const int* in_sizes, int n_in,
                              void* d_out, int out_size, void* d_ws, size_t ws_size,
                              hipStream_t stream) {
  const float* x_gene = (const float*)d_in[0];
  const float* x_pheno = (const float*)d_in[1];
  const int* ei_gp = (const int*)d_in[2];
  const int* ei_pg = (const int*)d_in[3];
  const int* ei_gg = (const int*)d_in[4];
  const float* W_gp = (const float*)d_in[5];
  const float* a_s_gp = (const float*)d_in[6];
  const float* a_d_gp = (const float*)d_in[7];
  const float* b_gp = (const float*)d_in[8];
  const float* W_pg = (const float*)d_in[9];
  const float* a_s_pg = (const float*)d_in[10];
  const float* a_d_pg = (const float*)d_in[11];
  const float* b_pg = (const float*)d_in[12];
  const float* W_gg = (const float*)d_in[13];
  const float* a_s_gg = (const float*)d_in[14];
  const float* a_d_gg = (const float*)d_in[15];
  const float* b_gg = (const float*)d_in[16];
  const float* ln_g_gene = (const float*)d_in[17];
  const float* ln_b_gene = (const float*)d_in[18];
  const float* ln_g_ph = (const float*)d_in[19];
  const float* ln_b_ph = (const float*)d_in[20];
  float* out = (float*)d_out;

  float* ws = (float*)d_ws;
  ushort* hb3 = (ushort*)ws;                    // 3 x 12.8M bf16 = 19.2M f32
  ushort* xb = (ushort*)(ws + 19200000);        // 100352 rows x 256 bf16
  ushort* alsb = (ushort*)(ws + 32060000);      // 3 x 400k bf16 = 600k f32
  float* ald3 = ws + 32700000;                  // 3 x 400k f32
  ushort* WT = (ushort*)(ws + 33960000);        // 3 x 65536 bf16
  ushort* V6T = (ushort*)(ws + 34060000);       // 64 x 256 bf16
  int* ibase = (int*)(ws + 34080000);
  int* cnt3 = ibase;                            // 150016
  int* srcs3 = ibase + 150016;                  // 150000 * CAP = 9.6M ints

  // ---------- prep: WT, V6T, xb, cnt3-zero (one dispatch) ----------
  prep_kernel<<<305 + 2048, 256, 0, stream>>>(
      W_gp, W_pg, W_gg, a_s_gp, a_s_pg, a_s_gg, a_d_gp, a_d_pg, a_d_gg,
      x_gene, x_pheno, WT, V6T, xb, cnt3);

  // ---------- bucket-permute + h GEMMs (128x128) + al projections ----------
  fused_compute<<<dim3(391, 8), 256, 0, stream>>>(xb, WT, V6T, hb3, alsb, ald3,
                                                  ei_gp, ei_pg, ei_gg, cnt3, srcs3);

  // ---------- gather + residual + bias + LayerNorm ----------
  gat_gather_ln<<<(2 * NN + 3) / 4, 256, 0, stream>>>(
      cnt3, srcs3, hb3, alsb, ald3, xb, b_gp, b_pg, b_gg,
      ln_g_gene, ln_b_gene, ln_g_ph, ln_b_ph, out);
}

// Round 18
// 297.607 us; speedup vs baseline: 1.0143x; 1.0143x over previous
//
#include <hip/hip_runtime.h>

#define NN 50000
#define EE 500000
#define CAP 64  // per-dst slot capacity; deg ~ Poisson(10), P(deg>=64) ~ e^-65

typedef unsigned int u32;
typedef unsigned short ushort;
typedef __attribute__((ext_vector_type(8))) short short8v;
typedef __attribute__((ext_vector_type(4))) float float4v;

__device__ __forceinline__ ushort f2b(float f) {  // f32 -> bf16 RNE
  u32 u = __float_as_uint(f);
  u32 r = (u + 0x7fffu + ((u >> 16) & 1u)) >> 16;
  return (ushort)r;
}
__device__ __forceinline__ u32 pk2(float a, float b) {
  return (u32)f2b(a) | ((u32)f2b(b) << 16);
}
__device__ __forceinline__ float bl(u32 q) { return __uint_as_float(q << 16); }
__device__ __forceinline__ float bh(u32 q) { return __uint_as_float(q & 0xffff0000u); }
__device__ __forceinline__ void gload16(const void* g, void* l) {
  __builtin_amdgcn_global_load_lds((const __attribute__((address_space(1))) void*)g,
                                   (__attribute__((address_space(3))) void*)l, 16, 0, 0);
}

// -------- prep: WT transpose | V6T fold | pad | xb convert + cnt3 zero --------
__global__ void prep_kernel(const float* __restrict__ W_gp, const float* __restrict__ W_pg,
                            const float* __restrict__ W_gg,
                            const float* __restrict__ as_gp, const float* __restrict__ as_pg,
                            const float* __restrict__ as_gg,
                            const float* __restrict__ ad_gp, const float* __restrict__ ad_pg,
                            const float* __restrict__ ad_gg,
                            const float* __restrict__ xg, const float* __restrict__ xp,
                            ushort* __restrict__ WT, ushort* __restrict__ V6T,
                            ushort* __restrict__ xb, int* __restrict__ cnt3) {
  int b = blockIdx.x;
  int k = threadIdx.x;
  if (b < 256) {  // weight transposes: WT[p][n][k] = W_p[k][n]
    int n = b;
    WT[(size_t)0 * 65536 + n * 256 + k] = f2b(W_gp[k * 256 + n]);
    WT[(size_t)1 * 65536 + n * 256 + k] = f2b(W_pg[k * 256 + n]);
    WT[(size_t)2 * 65536 + n * 256 + k] = f2b(W_gg[k * 256 + n]);
    return;
  }
  if (b < 304) {  // V6T fold: one block per (g,h); v[k] = sum_c W[k][32h+c]*a[h][c]
    int idx = b - 256;
    int g = idx >> 3, h = idx & 7;
    const float* W;
    const float* a;
    switch (g) {
      case 0: W = W_gp; a = as_gp; break;  // als gp (gene rows)
      case 1: W = W_gg; a = as_gg; break;  // als gg (gene rows)
      case 2: W = W_pg; a = ad_pg; break;  // ald pg (gene rows, dst)
      case 3: W = W_gg; a = ad_gg; break;  // ald gg (gene rows, dst)
      case 4: W = W_pg; a = as_pg; break;  // als pg (pheno rows)
      default: W = W_gp; a = ad_gp; break; // ald gp (pheno rows, dst)
    }
    const float4* wrow = (const float4*)&W[(size_t)k * 256 + h * 32];
    const float4* arow = (const float4*)&a[h * 32];
    float s = 0.f;
#pragma unroll
    for (int q = 0; q < 8; ++q) {
      float4 wv = wrow[q];
      float4 av = arow[q];
      s += wv.x * av.x + wv.y * av.y + wv.z * av.z + wv.w * av.w;
    }
    V6T[(size_t)(g * 8 + h) * 256 + k] = f2b(s);
    return;
  }
  if (b == 304) {  // pad cols 48..63
#pragma unroll
    for (int col = 48; col < 64; ++col) V6T[(size_t)col * 256 + k] = 0;
    return;
  }
  // xb convert + cnt3 zero (prep precedes fused_compute, so ordering holds)
  int gid = (b - 305) * 256 + k;
  const int gstride = 2048 * 256;
  for (int j = gid; j < 3 * NN; j += gstride) cnt3[j] = 0;
  const int tot = 2 * NN * 64;
  for (int i = gid; i < tot; i += gstride) {
    const float* src = (i < NN * 64) ? xg + (size_t)i * 4 : xp + ((size_t)i - (size_t)NN * 64) * 4;
    float4 v = *(const float4*)src;
    ushort4 o;
    o.x = f2b(v.x); o.y = f2b(v.y); o.z = f2b(v.z); o.w = f2b(v.w);
    *(ushort4*)&xb[(size_t)i * 4] = o;
  }
}

// ---------------- fused compute: y==0 bucket-permute | y in [1,6] h-GEMM (128x128) | y==7 al ----------------
__global__ __launch_bounds__(256) void fused_compute(
    const ushort* __restrict__ xb, const ushort* __restrict__ WT,
    const ushort* __restrict__ V6T, ushort* __restrict__ hb3,
    ushort* __restrict__ alsb, float* __restrict__ ald3,
    const int* __restrict__ e0, const int* __restrict__ e1, const int* __restrict__ e2,
    int* __restrict__ cnt3, ushort* __restrict__ srcs3) {
  __shared__ ushort smem[16384];  // 32 KB: GEMM As 2x4096 | Bs 2x4096 ; al uses first 2x2048
  const int tid = threadIdx.x;
  const int l = tid & 63, w = tid >> 6;
  const int rr = l & 15, kb = l >> 4;
  if (blockIdx.y == 0) {
    // bucket permute: srcs3[slot*CAP + cnt3[slot]++] = src  (cnt3 zeroed by prep)
    // Counted, fully-unrolled loop -> 15 independent load/atomic/store chains per
    // thread in flight (latency hiding); srcs3 is ushort (19.2 MB footprint, ~L2).
    const int T = 391 * 256;
    const int base = blockIdx.x * 256 + tid;
#pragma unroll
    for (int it = 0; it < 15; ++it) {
      int i = base + it * T;
      if (i < 3 * EE) {
        int which = i >= 2 * EE ? 2 : (i >= EE ? 1 : 0);
        const int* ei = which == 0 ? e0 : (which == 1 ? e1 : e2);
        int e = i - which * EE;
        int d = ei[EE + e];
        int s = ei[e];
        int gslot = which * NN + d;
        int pos = atomicAdd(&cnt3[gslot], 1);
        if (pos < CAP) srcs3[(size_t)gslot * CAP + pos] = (ushort)s;
      }
    }
    return;
  }
  if (blockIdx.y < 7) {
    ushort* As = smem;          // [2][4096]
    ushort* Bs = smem + 8192;   // [2][4096]
    const int yy = blockIdx.y - 1;
    const int p = yy >> 1;
    const int c0 = (yy & 1) * 128;
    const ushort* x = xb + (p == 1 ? (size_t)NN * 256 : 0);
    const ushort* Wp = WT + (size_t)p * 65536 + (size_t)c0 * 256;
    ushort* hb = hb3 + (size_t)p * 12800000;
    const int r0 = blockIdx.x * 128;
    const int wm = w >> 1, wn = w & 1;
    float4v acc[4][4];
#pragma unroll
    for (int mi = 0; mi < 4; ++mi)
#pragma unroll
      for (int ni = 0; ni < 4; ++ni) acc[mi][ni] = (float4v){0.f, 0.f, 0.f, 0.f};
    const int r1 = tid >> 2, g1 = tid & 3;
    const int r2 = 64 + (tid >> 2), g2 = tid & 3;

#define STAGE(buf, k0)                                                               \
  {                                                                                  \
    gload16(&x[(size_t)(r0 + r1) * 256 + (k0) + g1 * 8], &As[(buf) * 4096 + tid * 8]); \
    gload16(&x[(size_t)(r0 + r2) * 256 + (k0) + g2 * 8], &As[(buf) * 4096 + (tid + 256) * 8]); \
    gload16(&Wp[(size_t)r1 * 256 + (k0) + g1 * 8], &Bs[(buf) * 4096 + tid * 8]);     \
    gload16(&Wp[(size_t)r2 * 256 + (k0) + g2 * 8], &Bs[(buf) * 4096 + (tid + 256) * 8]); \
  }

    STAGE(0, 0);
    __syncthreads();
#pragma unroll
    for (int k = 0; k < 8; ++k) {
      const int buf = k & 1;
      if (k < 7) STAGE(buf ^ 1, (k + 1) * 32);
      short8v af[4], bf[4];
#pragma unroll
      for (int t = 0; t < 4; ++t) {
        af[t] = *(const short8v*)&As[buf * 4096 + (wm * 64 + t * 16 + rr) * 32 + kb * 8];
        bf[t] = *(const short8v*)&Bs[buf * 4096 + (wn * 64 + t * 16 + rr) * 32 + kb * 8];
      }
#pragma unroll
      for (int mi = 0; mi < 4; ++mi)
#pragma unroll
        for (int ni = 0; ni < 4; ++ni)
          acc[mi][ni] = __builtin_amdgcn_mfma_f32_16x16x32_bf16(bf[ni], af[mi], acc[mi][ni], 0, 0, 0);
      __syncthreads();
    }
#undef STAGE
#pragma unroll
    for (int mi = 0; mi < 4; ++mi) {
      const int row = r0 + wm * 64 + mi * 16 + rr;
      if (row < NN) {
        ushort* hp = &hb[(size_t)row * 256 + c0 + wn * 64 + kb * 4];
#pragma unroll
        for (int ni = 0; ni < 4; ++ni) {
          uint2 o;
          o.x = pk2(acc[mi][ni][0], acc[mi][ni][1]);
          o.y = pk2(acc[mi][ni][2], acc[mi][ni][3]);
          *(uint2*)&hp[ni * 16] = o;
        }
      }
    }
    return;
  }
  // ---- al slice: 256 rows per block; V6T fragments preloaded to registers ----
  ushort* As2 = smem;  // [2][2048]
  short8v bfv[8];
#pragma unroll
  for (int k = 0; k < 8; ++k) {
    uint4 q = *(const uint4*)&V6T[(size_t)(w * 16 + rr) * 256 + k * 32 + kb * 8];
    bfv[k] = *(short8v*)&q;
  }
  for (int t = 0; t < 4; ++t) {
    const int r0 = blockIdx.x * 256 + t * 64;
    gload16(&xb[(size_t)(r0 + (tid >> 2)) * 256 + (tid & 3) * 8], &As2[tid * 8]);
    __syncthreads();
    float4v acc[4];
#pragma unroll
    for (int mi = 0; mi < 4; ++mi) acc[mi] = (float4v){0.f, 0.f, 0.f, 0.f};
#pragma unroll
    for (int k = 0; k < 8; ++k) {
      const int buf = k & 1;
      if (k < 7)
        gload16(&xb[(size_t)(r0 + (tid >> 2)) * 256 + (k + 1) * 32 + (tid & 3) * 8],
                &As2[(buf ^ 1) * 2048 + tid * 8]);
#pragma unroll
      for (int mi = 0; mi < 4; ++mi) {
        short8v afv = *(const short8v*)&As2[buf * 2048 + (mi * 16 + rr) * 32 + kb * 8];
        acc[mi] = __builtin_amdgcn_mfma_f32_16x16x32_bf16(bfv[k], afv, acc[mi], 0, 0, 0);
      }
      __syncthreads();
    }
    // lane holds D[row=r0+mi*16+rr][col=w*16+kb*4+i]; g=w*2+(kb>>1); idx=(kb&1)*4
    const int g = w * 2 + (kb >> 1);
    const int idx = (kb & 1) * 4;
#pragma unroll
    for (int mi = 0; mi < 4; ++mi) {
      int grow = r0 + mi * 16 + rr;
      float4 val = make_float4(acc[mi][0], acc[mi][1], acc[mi][2], acc[mi][3]);
      if (grow < NN) {
        if (g == 0 || g == 1) {
          ushort* arr = alsb + (g == 0 ? 0 : 800000);
          uint2 o;
          o.x = pk2(val.x, val.y);
          o.y = pk2(val.z, val.w);
          *(uint2*)&arr[(size_t)grow * 8 + idx] = o;
        } else if (g == 2 || g == 3) {
          float* arr = ald3 + (g == 2 ? 400000 : 800000);
          *(float4*)&arr[(size_t)grow * 8 + idx] = val;
        }
      } else if (grow < 2 * NN) {
        int r = grow - NN;
        if (g == 4) {
          uint2 o;
          o.x = pk2(val.x, val.y);
          o.y = pk2(val.z, val.w);
          *(uint2*)&alsb[400000 + (size_t)r * 8 + idx] = o;
        } else if (g == 5) {
          *(float4*)&ald3[(size_t)r * 8 + idx] = val;
        }
      }
    }
  }
}

// -------- gather+LN: one wave per output row; gene waves do pg+gg; fused LN --------
__global__ __launch_bounds__(256) void gat_gather_ln(
    const int* __restrict__ cnt3, const ushort* __restrict__ srcs3,
    const ushort* __restrict__ hb3, const ushort* __restrict__ alsb,
    const float* __restrict__ ald3, const ushort* __restrict__ xb,
    const float* __restrict__ b_gp, const float* __restrict__ b_pg,
    const float* __restrict__ b_gg,
    const float* __restrict__ lng_g, const float* __restrict__ lnb_g,
    const float* __restrict__ lng_p, const float* __restrict__ lnb_p,
    float* __restrict__ out) {
  __shared__ float exs[4][8][68];
  __shared__ int ssrc[4][64];
  const int l = threadIdx.x & 63;
  const int wv = threadIdx.x >> 6;
  const int slot = blockIdx.x * 4 + wv;
  if (slot >= 2 * NN) return;
  const bool gene = (slot < NN);
  const int d = gene ? slot : slot - NN;
  const int sl = l & 31;
  const int half = l >> 5;
  const int hh = sl >> 2;
  float vout[8] = {0.f, 0.f, 0.f, 0.f, 0.f, 0.f, 0.f, 0.f};
  const int nph = gene ? 2 : 1;
  for (int q = 0; q < nph; ++q) {
    const int phase = gene ? (1 + q) : 0;
    const int cslot = phase * NN + d;
    const ushort* hmat = hb3 + (size_t)phase * 12800000;
    const ushort* al_s = alsb + (size_t)phase * 400000;
    const float* al_d = ald3 + (size_t)phase * 400000;
    const int cnt = cnt3[cslot];
    if (cnt == 0) continue;
    const ushort* srow = srcs3 + (size_t)cslot * CAP;
    float4 ad0 = *(const float4*)&al_d[(size_t)d * 8];
    float4 ad1 = *(const float4*)&al_d[(size_t)d * 8 + 4];
    const float ald[8] = {ad0.x, ad0.y, ad0.z, ad0.w, ad1.x, ad1.y, ad1.z, ad1.w};
    float den = 0.f;
    float acc8[8] = {0.f, 0.f, 0.f, 0.f, 0.f, 0.f, 0.f, 0.f};
    const ushort* hrow = hmat + sl * 8;
    // cnt <= CAP = 64: single chunk
    {
      float ex[8] = {0.f, 0.f, 0.f, 0.f, 0.f, 0.f, 0.f, 0.f};
      int s = 0;
      if (l < cnt) {
        s = srow[l];
        uint4 sq = *(const uint4*)&al_s[(size_t)s * 8];
        float a[8] = {bl(sq.x) + ald[0], bh(sq.x) + ald[1], bl(sq.y) + ald[2], bh(sq.y) + ald[3],
                      bl(sq.z) + ald[4], bh(sq.z) + ald[5], bl(sq.w) + ald[6], bh(sq.w) + ald[7]};
#pragma unroll
        for (int h = 0; h < 8; ++h) ex[h] = __expf(fmaxf(a[h], 0.2f * a[h]));
      }
      ssrc[wv][l] = s;
#pragma unroll
      for (int h = 0; h < 8; ++h) exs[wv][h][l] = ex[h];
      // 2 edges per half in flight
      int chunkr = (cnt + 3) & ~3;
      for (int j = 0; j < chunkr; j += 4) {
        int ja = j + half, jb = j + 2 + half;
        int sa = ssrc[wv][ja], sb = ssrc[wv][jb];
        float wa = exs[wv][hh][ja], wb = exs[wv][hh][jb];
        uint4 pa = *(const uint4*)&hrow[(size_t)sa * 256];
        uint4 pb = *(const uint4*)&hrow[(size_t)sb * 256];
        den += wa + wb;
        acc8[0] += bl(pa.x) * wa + bl(pb.x) * wb;
        acc8[1] += bh(pa.x) * wa + bh(pb.x) * wb;
        acc8[2] += bl(pa.y) * wa + bl(pb.y) * wb;
        acc8[3] += bh(pa.y) * wa + bh(pb.y) * wb;
        acc8[4] += bl(pa.z) * wa + bl(pb.z) * wb;
        acc8[5] += bh(pa.z) * wa + bh(pb.z) * wb;
        acc8[6] += bl(pa.w) * wa + bl(pb.w) * wb;
        acc8[7] += bh(pa.w) * wa + bh(pb.w) * wb;
      }
    }
#pragma unroll
    for (int i = 0; i < 8; ++i) acc8[i] += __shfl_xor(acc8[i], 32);
    den += __shfl_xor(den, 32);
    float wd = 1.f / (den + 1e-16f);
#pragma unroll
    for (int i = 0; i < 8; ++i) vout[i] += acc8[i] * wd;
  }
  // residual (bf16 xb) + biases
  const ushort* xrow = xb + (gene ? 0 : (size_t)NN * 256) + (size_t)d * 256;
  uint4 xq = *(const uint4*)&xrow[sl * 8];
  float4 ba, bb;
  if (gene) {
    float4 p1 = *(const float4*)&b_pg[sl * 8];
    float4 p2 = *(const float4*)&b_pg[sl * 8 + 4];
    float4 q1 = *(const float4*)&b_gg[sl * 8];
    float4 q2 = *(const float4*)&b_gg[sl * 8 + 4];
    ba = make_float4(p1.x + q1.x, p1.y + q1.y, p1.z + q1.z, p1.w + q1.w);
    bb = make_float4(p2.x + q2.x, p2.y + q2.y, p2.z + q2.z, p2.w + q2.w);
  } else {
    ba = *(const float4*)&b_gp[sl * 8];
    bb = *(const float4*)&b_gp[sl * 8 + 4];
  }
  vout[0] += bl(xq.x) + ba.x; vout[1] += bh(xq.x) + ba.y;
  vout[2] += bl(xq.y) + ba.z; vout[3] += bh(xq.y) + ba.w;
  vout[4] += bl(xq.z) + bb.x; vout[5] += bh(xq.z) + bb.y;
  vout[6] += bl(xq.w) + bb.z; vout[7] += bh(xq.w) + bb.w;
  // LayerNorm over 256 ch (32 lanes x 8; halves duplicate)
  float s = 0.f, ss = 0.f;
#pragma unroll
  for (int i = 0; i < 8; ++i) { s += vout[i]; ss += vout[i] * vout[i]; }
#pragma unroll
  for (int off = 1; off < 32; off <<= 1) {
    s += __shfl_xor(s, off);
    ss += __shfl_xor(ss, off);
  }
  float mu = s * (1.f / 256.f);
  float var = ss * (1.f / 256.f) - mu * mu;
  float rstd = rsqrtf(var + 1e-5f);
  const float* lg = gene ? lng_g : lng_p;
  const float* lb = gene ? lnb_g : lnb_p;
  float4 g1 = *(const float4*)&lg[sl * 8];
  float4 g2 = *(const float4*)&lg[sl * 8 + 4];
  float4 c1 = *(const float4*)&lb[sl * 8];
  float4 c2 = *(const float4*)&lb[sl * 8 + 4];
  if (half == 0) {
    float* op = &out[(size_t)slot * 256 + sl * 8];
    float4 o1 = make_float4((vout[0] - mu) * rstd * g1.x + c1.x,
                            (vout[1] - mu) * rstd * g1.y + c1.y,
                            (vout[2] - mu) * rstd * g1.z + c1.z,
                            (vout[3] - mu) * rstd * g1.w + c1.w);
    float4 o2 = make_float4((vout[4] - mu) * rstd * g2.x + c2.x,
                            (vout[5] - mu) * rstd * g2.y + c2.y,
                            (vout[6] - mu) * rstd * g2.z + c2.z,
                            (vout[7] - mu) * rstd * g2.w + c2.w);
    *(float4*)op = o1;
    *(float4*)(op + 4) = o2;
  }
}

extern "C" void kernel_launch(void* const* d_in, const int* in_sizes, int n_in,
                              void* d_out, int out_size, void* d_ws, size_t ws_size,
                              hipStream_t stream) {
  const float* x_gene = (const float*)d_in[0];
  const float* x_pheno = (const float*)d_in[1];
  const int* ei_gp = (const int*)d_in[2];
  const int* ei_pg = (const int*)d_in[3];
  const int* ei_gg = (const int*)d_in[4];
  const float* W_gp = (const float*)d_in[5];
  const float* a_s_gp = (const float*)d_in[6];
  const float* a_d_gp = (const float*)d_in[7];
  const float* b_gp = (const float*)d_in[8];
  const float* W_pg = (const float*)d_in[9];
  const float* a_s_pg = (const float*)d_in[10];
  const float* a_d_pg = (const float*)d_in[11];
  const float* b_pg = (const float*)d_in[12];
  const float* W_gg = (const float*)d_in[13];
  const float* a_s_gg = (const float*)d_in[14];
  const float* a_d_gg = (const float*)d_in[15];
  const float* b_gg = (const float*)d_in[16];
  const float* ln_g_gene = (const float*)d_in[17];
  const float* ln_b_gene = (const float*)d_in[18];
  const float* ln_g_ph = (const float*)d_in[19];
  const float* ln_b_ph = (const float*)d_in[20];
  float* out = (float*)d_out;

  float* ws = (float*)d_ws;
  ushort* hb3 = (ushort*)ws;                    // 3 x 12.8M bf16 = 19.2M f32
  ushort* xb = (ushort*)(ws + 19200000);        // 100352 rows x 256 bf16
  ushort* alsb = (ushort*)(ws + 32060000);      // 3 x 400k bf16 = 600k f32
  float* ald3 = ws + 32700000;                  // 3 x 400k f32
  ushort* WT = (ushort*)(ws + 33960000);        // 3 x 65536 bf16
  ushort* V6T = (ushort*)(ws + 34060000);       // 64 x 256 bf16
  int* ibase = (int*)(ws + 34080000);
  int* cnt3 = ibase;                            // 150016 ints
  ushort* srcs3 = (ushort*)(ibase + 150016);    // 150000 * CAP ushorts = 19.2 MB

  // ---------- prep: WT, V6T, xb, cnt3-zero (one dispatch) ----------
  prep_kernel<<<305 + 2048, 256, 0, stream>>>(
      W_gp, W_pg, W_gg, a_s_gp, a_s_pg, a_s_gg, a_d_gp, a_d_pg, a_d_gg,
      x_gene, x_pheno, WT, V6T, xb, cnt3);

  // ---------- bucket-permute + h GEMMs (128x128) + al projections ----------
  fused_compute<<<dim3(391, 8), 256, 0, stream>>>(xb, WT, V6T, hb3, alsb, ald3,
                                                  ei_gp, ei_pg, ei_gg, cnt3, srcs3);

  // ---------- gather + residual + bias + LayerNorm ----------
  gat_gather_ln<<<(2 * NN + 3) / 4, 256, 0, stream>>>(
      cnt3, srcs3, hb3, alsb, ald3, xb, b_gp, b_pg, b_gg,
      ln_g_gene, ln_b_gene, ln_g_ph, ln_b_ph, out);
}